// Round 1
// baseline (2561.659 us; speedup 1.0000x reference)
//
#include <hip/hip_runtime.h>
#include <hip/hip_bf16.h>

#define B_ 4
#define N_ 10000
#define E_ 160000
#define D_ 128
#define H_ 4
#define HID_ 128
#define DK_ 32
#define DE_ 16

// ---------------------------------------------------------------------------
// K1: fused QKV projection.  x:(B*N,128) @ {Wq,Wk,Wv}:(128,128) + bias
// block = 256 threads = 4 waves; block handles 8 rows (2 rows / wave).
// ---------------------------------------------------------------------------
__global__ __launch_bounds__(256) void qkv_proj(
    const float* __restrict__ x,
    const float* __restrict__ Wq, const float* __restrict__ bq,
    const float* __restrict__ Wk, const float* __restrict__ bk,
    const float* __restrict__ Wv, const float* __restrict__ bv,
    float* __restrict__ Q, float* __restrict__ Kt, float* __restrict__ V) {
  __shared__ float xs[8][128];
  const int tid  = threadIdx.x;
  const int lane = tid & 63;
  const int wave = tid >> 6;
  const long rowBase = (long)blockIdx.x * 8;

  for (int i = tid; i < 8 * 128; i += 256)
    xs[i >> 7][i & 127] = x[rowBase * 128 + i];
  __syncthreads();

  const int r0 = wave * 2, r1 = wave * 2 + 1;
  const float* Ws[3] = {Wq, Wk, Wv};
  const float* bs[3] = {bq, bk, bv};
  float* Os[3] = {Q, Kt, V};

#pragma unroll
  for (int m = 0; m < 3; ++m) {
    const float* W = Ws[m];
    float acc00 = bs[m][lane], acc01 = bs[m][lane + 64];
    float acc10 = acc00, acc11 = acc01;
#pragma unroll 4
    for (int k = 0; k < 128; ++k) {
      const float w0 = W[k * 128 + lane];
      const float w1 = W[k * 128 + 64 + lane];
      const float a0 = xs[r0][k];
      const float a1 = xs[r1][k];
      acc00 = fmaf(a0, w0, acc00);
      acc01 = fmaf(a0, w1, acc01);
      acc10 = fmaf(a1, w0, acc10);
      acc11 = fmaf(a1, w1, acc11);
    }
    float* O = Os[m];
    O[(rowBase + r0) * 128 + lane]      = acc00;
    O[(rowBase + r0) * 128 + 64 + lane] = acc01;
    O[(rowBase + r1) * 128 + lane]      = acc10;
    O[(rowBase + r1) * 128 + 64 + lane] = acc11;
  }
}

// ---------------------------------------------------------------------------
// K2: per-edge FiLM + logits + exp + segment-sum (no max pass: logits are
// O(0.05) so exp(lg)/sum(exp(lg)) == reference softmax up to fp32 rounding).
// block = 256 = 4 waves; each wave loops over 16 edges (64 edges / block).
// lane decomposition: b = lane>>4, h = (lane>>2)&3, q = lane&3; 8 dk / lane.
// ---------------------------------------------------------------------------
__global__ __launch_bounds__(256) void edge_logits(
    const int* __restrict__ ei, const float* __restrict__ ea,
    const float* __restrict__ Wf, const float* __restrict__ bf,
    const float* __restrict__ Q, const float* __restrict__ Kt,
    float* __restrict__ ex, float* __restrict__ s) {
  __shared__ float wf[16 * 256];
  __shared__ float bfs[256];
  __shared__ float gb[4][256];  // per-wave gamma(0..127) / beta(128..255)

  const int tid = threadIdx.x;
  for (int i = tid; i < 16 * 256; i += 256) wf[i] = Wf[i];
  if (tid < 256) bfs[tid] = bf[tid];
  __syncthreads();

  const int lane = tid & 63;
  const int wave = tid >> 6;
  const int b = lane >> 4, h = (lane >> 2) & 3, q = lane & 3;
  const int cbase = h * 32 + q * 8;

  const float4* wf4  = (const float4*)wf;
  const float4* bfs4 = (const float4*)bfs;

  for (int it = 0; it < 16; ++it) {
    const int e = blockIdx.x * 64 + it * 4 + wave;
    const int src = ei[e];
    const int dst = ei[E_ + e];

    // edge_attr[e][0..15]
    float eav[16];
    {
      const float4* eap = (const float4*)(ea + (size_t)e * 16);
      float4 t0 = eap[0], t1 = eap[1], t2 = eap[2], t3 = eap[3];
      eav[0]=t0.x; eav[1]=t0.y; eav[2]=t0.z; eav[3]=t0.w;
      eav[4]=t1.x; eav[5]=t1.y; eav[6]=t1.z; eav[7]=t1.w;
      eav[8]=t2.x; eav[9]=t2.y; eav[10]=t2.z; eav[11]=t2.w;
      eav[12]=t3.x; eav[13]=t3.y; eav[14]=t3.z; eav[15]=t3.w;
    }

    // cooperative gamma/beta: lane computes the 4 cols [lane*4, lane*4+4)
    float4 accg = bfs4[lane];
#pragma unroll
    for (int de = 0; de < 16; ++de) {
      const float ev = eav[de];
      const float4 w = wf4[de * 64 + lane];
      accg.x = fmaf(ev, w.x, accg.x);
      accg.y = fmaf(ev, w.y, accg.y);
      accg.z = fmaf(ev, w.z, accg.z);
      accg.w = fmaf(ev, w.w, accg.w);
    }
    ((float4*)gb[wave])[lane] = accg;
    __syncthreads();

    const float4* gbp = (const float4*)gb[wave];
    const float4 g0 = gbp[(cbase >> 2)];
    const float4 g1 = gbp[(cbase >> 2) + 1];
    const float4 t0 = gbp[32 + (cbase >> 2)];
    const float4 t1 = gbp[32 + (cbase >> 2) + 1];

    const size_t qoff = ((size_t)b * N_ + dst) * 128 + cbase;
    const size_t koff = ((size_t)b * N_ + src) * 128 + cbase;
    const float4 q0 = *(const float4*)(Q + qoff);
    const float4 q1 = *(const float4*)(Q + qoff + 4);
    const float4 k0 = *(const float4*)(Kt + koff);
    const float4 k1 = *(const float4*)(Kt + koff + 4);

    float p = 0.f;
    p = fmaf(q0.x, fmaf(k0.x, 1.f + g0.x, t0.x), p);
    p = fmaf(q0.y, fmaf(k0.y, 1.f + g0.y, t0.y), p);
    p = fmaf(q0.z, fmaf(k0.z, 1.f + g0.z, t0.z), p);
    p = fmaf(q0.w, fmaf(k0.w, 1.f + g0.w, t0.w), p);
    p = fmaf(q1.x, fmaf(k1.x, 1.f + g1.x, t1.x), p);
    p = fmaf(q1.y, fmaf(k1.y, 1.f + g1.y, t1.y), p);
    p = fmaf(q1.z, fmaf(k1.z, 1.f + g1.z, t1.z), p);
    p = fmaf(q1.w, fmaf(k1.w, 1.f + g1.w, t1.w), p);

    p += __shfl_xor(p, 1);
    p += __shfl_xor(p, 2);

    const float lg = p * 0.17677669529663687f;  // 1/sqrt(32)
    const float exv = __expf(lg);
    if (q == 0) {
      ex[(size_t)e * 16 + b * 4 + h] = exv;
      atomicAdd(&s[((size_t)b * N_ + dst) * 4 + h], exv);
    }
    __syncthreads();
  }
}

// ---------------------------------------------------------------------------
// K3: att = ex / s[dst]; agg[b,dst,:] += att * V[b,src,:]  (fp32 atomics)
// wave per edge, same lane decomposition as K2.
// ---------------------------------------------------------------------------
__global__ __launch_bounds__(256) void edge_scatter(
    const int* __restrict__ ei, const float* __restrict__ ex,
    const float* __restrict__ s, const float* __restrict__ V,
    float* __restrict__ agg) {
  const int tid = threadIdx.x;
  const int lane = tid & 63;
  const int wave = tid >> 6;
  const int e = blockIdx.x * 4 + wave;
  const int src = ei[e];
  const int dst = ei[E_ + e];
  const int b = lane >> 4, h = (lane >> 2) & 3, q = lane & 3;
  const int cbase = h * 32 + q * 8;

  const float exv = ex[(size_t)e * 16 + b * 4 + h];
  const float sv  = s[((size_t)b * N_ + dst) * 4 + h];
  const float att = exv / sv;

  const size_t voff = ((size_t)b * N_ + src) * 128 + cbase;
  const float4 v0 = *(const float4*)(V + voff);
  const float4 v1 = *(const float4*)(V + voff + 4);

  float* ab = agg + ((size_t)b * N_ + dst) * 128 + cbase;
  atomicAdd(ab + 0, att * v0.x);
  atomicAdd(ab + 1, att * v0.y);
  atomicAdd(ab + 2, att * v0.z);
  atomicAdd(ab + 3, att * v0.w);
  atomicAdd(ab + 4, att * v1.x);
  atomicAdd(ab + 5, att * v1.y);
  atomicAdd(ab + 6, att * v1.z);
  atomicAdd(ab + 7, att * v1.w);
}

// ---------------------------------------------------------------------------
// K4: y = agg @ Wo + bo; h = x + y; LayerNorm(h) -> out
// block = 256 = 4 waves; wave per row; lane owns cols {lane, lane+64}.
// ---------------------------------------------------------------------------
__global__ __launch_bounds__(256) void out_ln(
    const float* __restrict__ agg, const float* __restrict__ Wo,
    const float* __restrict__ bo, const float* __restrict__ x,
    const float* __restrict__ lng, const float* __restrict__ lnb,
    float* __restrict__ out) {
  __shared__ float rs[4][128];
  const int tid = threadIdx.x;
  const int lane = tid & 63;
  const int wave = tid >> 6;
  const long row = (long)blockIdx.x * 4 + wave;

  for (int i = tid; i < 4 * 128; i += 256)
    rs[i >> 7][i & 127] = agg[(long)blockIdx.x * 4 * 128 + i];
  __syncthreads();

  float acc0 = bo[lane], acc1 = bo[lane + 64];
#pragma unroll 4
  for (int k = 0; k < 128; ++k) {
    const float a = rs[wave][k];
    acc0 = fmaf(a, Wo[k * 128 + lane], acc0);
    acc1 = fmaf(a, Wo[k * 128 + 64 + lane], acc1);
  }

  const float h0 = x[row * 128 + lane] + acc0;
  const float h1 = x[row * 128 + 64 + lane] + acc1;

  float s1 = h0 + h1;
  float s2 = fmaf(h0, h0, h1 * h1);
#pragma unroll
  for (int m = 1; m < 64; m <<= 1) {
    s1 += __shfl_xor(s1, m);
    s2 += __shfl_xor(s2, m);
  }
  const float mu  = s1 * (1.f / 128.f);
  const float var = s2 * (1.f / 128.f) - mu * mu;
  const float inv = rsqrtf(var + 1e-5f);

  out[row * 128 + lane]      = (h0 - mu) * inv * lng[lane] + lnb[lane];
  out[row * 128 + 64 + lane] = (h1 - mu) * inv * lng[lane + 64] + lnb[lane + 64];
}

// ---------------------------------------------------------------------------
extern "C" void kernel_launch(void* const* d_in, const int* in_sizes, int n_in,
                              void* d_out, int out_size, void* d_ws, size_t ws_size,
                              hipStream_t stream) {
  const float* x   = (const float*)d_in[0];
  const int*   ei  = (const int*)d_in[1];
  const float* ea  = (const float*)d_in[2];
  const float* Wq  = (const float*)d_in[3];
  const float* bq  = (const float*)d_in[4];
  const float* Wk  = (const float*)d_in[5];
  const float* bk  = (const float*)d_in[6];
  const float* Wv  = (const float*)d_in[7];
  const float* bv  = (const float*)d_in[8];
  const float* Wf  = (const float*)d_in[9];
  const float* bf  = (const float*)d_in[10];
  const float* Wo  = (const float*)d_in[11];
  const float* bo  = (const float*)d_in[12];
  const float* lng = (const float*)d_in[13];
  const float* lnb = (const float*)d_in[14];
  float* out = (float*)d_out;

  const size_t NQ = (size_t)B_ * N_ * HID_;  // 5,120,000
  float* ws  = (float*)d_ws;
  float* Q   = ws;
  float* Kt  = ws + NQ;
  float* V   = ws + 2 * NQ;
  float* agg = ws + 3 * NQ;
  float* s   = ws + 4 * NQ;                  // B*N*H = 160,000
  float* ex  = ws + 4 * NQ + (size_t)B_ * N_ * H_;  // E*16 = 2,560,000

  // zero agg + s (contiguous)
  hipMemsetAsync(agg, 0, (NQ + (size_t)B_ * N_ * H_) * sizeof(float), stream);

  qkv_proj<<<(B_ * N_) / 8, 256, 0, stream>>>(x, Wq, bq, Wk, bk, Wv, bv, Q, Kt, V);
  edge_logits<<<E_ / 64, 256, 0, stream>>>(ei, ea, Wf, bf, Q, Kt, ex, s);
  edge_scatter<<<E_ / 4, 256, 0, stream>>>(ei, ex, s, V, agg);
  out_ln<<<(B_ * N_) / 4, 256, 0, stream>>>(agg, Wo, bo, x, lng, lnb, out);
}

// Round 2
// 426.394 us; speedup vs baseline: 6.0077x; 6.0077x over previous
//
#include <hip/hip_runtime.h>
#include <hip/hip_bf16.h>

#define B_ 4
#define N_ 10000
#define E_ 160000
#define D_ 128
#define H_ 4
#define HID_ 128
#define DK_ 32
#define DE_ 16

// ---------------------------------------------------------------------------
// K1: fused QKV projection.  x:(B*N,128) @ {Wq,Wk,Wv}:(128,128) + bias
// block = 256 threads = 4 waves; block handles 8 rows (2 rows / wave).
// ---------------------------------------------------------------------------
__global__ __launch_bounds__(256) void qkv_proj(
    const float* __restrict__ x,
    const float* __restrict__ Wq, const float* __restrict__ bq,
    const float* __restrict__ Wk, const float* __restrict__ bk,
    const float* __restrict__ Wv, const float* __restrict__ bv,
    float* __restrict__ Q, float* __restrict__ Kt, float* __restrict__ V) {
  __shared__ float xs[8][128];
  const int tid  = threadIdx.x;
  const int lane = tid & 63;
  const int wave = tid >> 6;
  const long rowBase = (long)blockIdx.x * 8;

  for (int i = tid; i < 8 * 128; i += 256)
    xs[i >> 7][i & 127] = x[rowBase * 128 + i];
  __syncthreads();

  const int r0 = wave * 2, r1 = wave * 2 + 1;
  const float* Ws[3] = {Wq, Wk, Wv};
  const float* bs[3] = {bq, bk, bv};
  float* Os[3] = {Q, Kt, V};

#pragma unroll
  for (int m = 0; m < 3; ++m) {
    const float* W = Ws[m];
    float acc00 = bs[m][lane], acc01 = bs[m][lane + 64];
    float acc10 = acc00, acc11 = acc01;
#pragma unroll 4
    for (int k = 0; k < 128; ++k) {
      const float w0 = W[k * 128 + lane];
      const float w1 = W[k * 128 + 64 + lane];
      const float a0 = xs[r0][k];
      const float a1 = xs[r1][k];
      acc00 = fmaf(a0, w0, acc00);
      acc01 = fmaf(a0, w1, acc01);
      acc10 = fmaf(a1, w0, acc10);
      acc11 = fmaf(a1, w1, acc11);
    }
    float* O = Os[m];
    O[(rowBase + r0) * 128 + lane]      = acc00;
    O[(rowBase + r0) * 128 + 64 + lane] = acc01;
    O[(rowBase + r1) * 128 + lane]      = acc10;
    O[(rowBase + r1) * 128 + 64 + lane] = acc11;
  }
}

// ---------------------------------------------------------------------------
// CSR build: histogram by dst -> exclusive scan -> bucket scatter
// ---------------------------------------------------------------------------
__global__ __launch_bounds__(256) void csr_hist(const int* __restrict__ ei,
                                                int* __restrict__ cnt) {
  const int e = blockIdx.x * 256 + threadIdx.x;
  if (e < E_) atomicAdd(&cnt[ei[E_ + e]], 1);
}

__global__ __launch_bounds__(1024) void csr_scan(const int* __restrict__ cnt,
                                                 int* __restrict__ rowptr,
                                                 int* __restrict__ fill) {
  __shared__ int part[1024];
  const int t = threadIdx.x;
  int local[10];
  int sum = 0;
#pragma unroll
  for (int i = 0; i < 10; ++i) {
    const int idx = t * 10 + i;
    local[i] = sum;
    sum += (idx < N_) ? cnt[idx] : 0;
  }
  part[t] = sum;
  __syncthreads();
  for (int off = 1; off < 1024; off <<= 1) {
    const int v = (t >= off) ? part[t - off] : 0;
    __syncthreads();
    part[t] += v;
    __syncthreads();
  }
  const int excl = (t == 0) ? 0 : part[t - 1];
#pragma unroll
  for (int i = 0; i < 10; ++i) {
    const int idx = t * 10 + i;
    if (idx <= N_) {
      const int o = excl + local[i];
      rowptr[idx] = o;
      if (idx < N_) fill[idx] = o;
    }
  }
}

__global__ __launch_bounds__(256) void csr_scatter(const int* __restrict__ ei,
                                                   int* __restrict__ fill,
                                                   int* __restrict__ eord) {
  const int e = blockIdx.x * 256 + threadIdx.x;
  if (e < E_) {
    const int dst = ei[E_ + e];
    const int pos = atomicAdd(&fill[dst], 1);
    eord[pos] = e;
  }
}

// ---------------------------------------------------------------------------
// K2: per-edge FiLM + logits + exp (no max pass: logits are O(0.05) so
// exp(lg)/sum(exp(lg)) == reference softmax up to fp32 rounding).
// block = 256 = 4 waves; each wave loops over 16 edges (64 edges / block).
// lane decomposition: b = lane>>4, h = (lane>>2)&3, q = lane&3; 8 dk / lane.
// ---------------------------------------------------------------------------
__global__ __launch_bounds__(256) void edge_logits(
    const int* __restrict__ ei, const float* __restrict__ ea,
    const float* __restrict__ Wf, const float* __restrict__ bf,
    const float* __restrict__ Q, const float* __restrict__ Kt,
    float* __restrict__ ex) {
  __shared__ float wf[16 * 256];
  __shared__ float bfs[256];
  __shared__ float gb[4][256];  // per-wave gamma(0..127) / beta(128..255)

  const int tid = threadIdx.x;
  for (int i = tid; i < 16 * 256; i += 256) wf[i] = Wf[i];
  if (tid < 256) bfs[tid] = bf[tid];
  __syncthreads();

  const int lane = tid & 63;
  const int wave = tid >> 6;
  const int b = lane >> 4, h = (lane >> 2) & 3, q = lane & 3;
  const int cbase = h * 32 + q * 8;

  const float4* wf4  = (const float4*)wf;
  const float4* bfs4 = (const float4*)bfs;

  for (int it = 0; it < 16; ++it) {
    const int e = blockIdx.x * 64 + it * 4 + wave;
    const int src = ei[e];
    const int dst = ei[E_ + e];

    float eav[16];
    {
      const float4* eap = (const float4*)(ea + (size_t)e * 16);
      float4 t0 = eap[0], t1 = eap[1], t2 = eap[2], t3 = eap[3];
      eav[0]=t0.x; eav[1]=t0.y; eav[2]=t0.z; eav[3]=t0.w;
      eav[4]=t1.x; eav[5]=t1.y; eav[6]=t1.z; eav[7]=t1.w;
      eav[8]=t2.x; eav[9]=t2.y; eav[10]=t2.z; eav[11]=t2.w;
      eav[12]=t3.x; eav[13]=t3.y; eav[14]=t3.z; eav[15]=t3.w;
    }

    // cooperative gamma/beta: lane computes the 4 cols [lane*4, lane*4+4)
    float4 accg = bfs4[lane];
#pragma unroll
    for (int de = 0; de < 16; ++de) {
      const float ev = eav[de];
      const float4 w = wf4[de * 64 + lane];
      accg.x = fmaf(ev, w.x, accg.x);
      accg.y = fmaf(ev, w.y, accg.y);
      accg.z = fmaf(ev, w.z, accg.z);
      accg.w = fmaf(ev, w.w, accg.w);
    }
    ((float4*)gb[wave])[lane] = accg;
    __syncthreads();

    const float4* gbp = (const float4*)gb[wave];
    const float4 g0 = gbp[(cbase >> 2)];
    const float4 g1 = gbp[(cbase >> 2) + 1];
    const float4 t0 = gbp[32 + (cbase >> 2)];
    const float4 t1 = gbp[32 + (cbase >> 2) + 1];

    const size_t qoff = ((size_t)b * N_ + dst) * 128 + cbase;
    const size_t koff = ((size_t)b * N_ + src) * 128 + cbase;
    const float4 q0 = *(const float4*)(Q + qoff);
    const float4 q1 = *(const float4*)(Q + qoff + 4);
    const float4 k0 = *(const float4*)(Kt + koff);
    const float4 k1 = *(const float4*)(Kt + koff + 4);

    float p = 0.f;
    p = fmaf(q0.x, fmaf(k0.x, 1.f + g0.x, t0.x), p);
    p = fmaf(q0.y, fmaf(k0.y, 1.f + g0.y, t0.y), p);
    p = fmaf(q0.z, fmaf(k0.z, 1.f + g0.z, t0.z), p);
    p = fmaf(q0.w, fmaf(k0.w, 1.f + g0.w, t0.w), p);
    p = fmaf(q1.x, fmaf(k1.x, 1.f + g1.x, t1.x), p);
    p = fmaf(q1.y, fmaf(k1.y, 1.f + g1.y, t1.y), p);
    p = fmaf(q1.z, fmaf(k1.z, 1.f + g1.z, t1.z), p);
    p = fmaf(q1.w, fmaf(k1.w, 1.f + g1.w, t1.w), p);

    p += __shfl_xor(p, 1);
    p += __shfl_xor(p, 2);

    const float lg = p * 0.17677669529663687f;  // 1/sqrt(32)
    if (q == 0) ex[(size_t)e * 16 + b * 4 + h] = __expf(lg);
    __syncthreads();
  }
}

// ---------------------------------------------------------------------------
// K3: CSR gather aggregation. block per node; wave = batch.
// lane owns dims {lane, lane+64}; head of dim d is d>>5.
// Pass 1 sums ex over incident edges (softmax denom), pass 2 accumulates
// att*V[src] in registers; single non-atomic write of agg row.
// ---------------------------------------------------------------------------
__global__ __launch_bounds__(256) void agg_gather(
    const int* __restrict__ ei, const int* __restrict__ rowptr,
    const int* __restrict__ eord, const float* __restrict__ ex,
    const float* __restrict__ V, float* __restrict__ agg) {
  const int node = blockIdx.x;
  const int lane = threadIdx.x & 63;
  const int b    = threadIdx.x >> 6;
  const int beg = rowptr[node], end = rowptr[node + 1];

  const int myh = lane & 3;
  float se = 0.f;
  for (int i = beg; i < end; ++i) {
    const int e = eord[i];
    se += ex[(size_t)e * 16 + b * 4 + myh];
  }
  const int h0 = lane >> 5;          // head of dim 'lane'   (0/1)
  const float inv0 = 1.f / __shfl(se, h0);
  const float inv1 = 1.f / __shfl(se, 2 + h0);  // head of dim 'lane+64' (2/3)

  float acc0 = 0.f, acc1 = 0.f;
  for (int i = beg; i < end; ++i) {
    const int e = eord[i];
    const int src = ei[e];
    const float* exp_ = ex + (size_t)e * 16 + b * 4;
    const float a0 = exp_[h0] * inv0;
    const float a1 = exp_[2 + h0] * inv1;
    const float* vp = V + ((size_t)b * N_ + src) * 128;
    acc0 = fmaf(a0, vp[lane], acc0);
    acc1 = fmaf(a1, vp[lane + 64], acc1);
  }
  float* ap = agg + ((size_t)b * N_ + node) * 128;
  ap[lane]      = acc0;
  ap[lane + 64] = acc1;
}

// ---------------------------------------------------------------------------
// K4: y = agg @ Wo + bo; h = x + y; LayerNorm(h) -> out
// ---------------------------------------------------------------------------
__global__ __launch_bounds__(256) void out_ln(
    const float* __restrict__ agg, const float* __restrict__ Wo,
    const float* __restrict__ bo, const float* __restrict__ x,
    const float* __restrict__ lng, const float* __restrict__ lnb,
    float* __restrict__ out) {
  __shared__ float rs[4][128];
  const int tid = threadIdx.x;
  const int lane = tid & 63;
  const int wave = tid >> 6;
  const long row = (long)blockIdx.x * 4 + wave;

  for (int i = tid; i < 4 * 128; i += 256)
    rs[i >> 7][i & 127] = agg[(long)blockIdx.x * 4 * 128 + i];
  __syncthreads();

  float acc0 = bo[lane], acc1 = bo[lane + 64];
#pragma unroll 4
  for (int k = 0; k < 128; ++k) {
    const float a = rs[wave][k];
    acc0 = fmaf(a, Wo[k * 128 + lane], acc0);
    acc1 = fmaf(a, Wo[k * 128 + 64 + lane], acc1);
  }

  const float h0 = x[row * 128 + lane] + acc0;
  const float h1 = x[row * 128 + 64 + lane] + acc1;

  float s1 = h0 + h1;
  float s2 = fmaf(h0, h0, h1 * h1);
#pragma unroll
  for (int m = 1; m < 64; m <<= 1) {
    s1 += __shfl_xor(s1, m);
    s2 += __shfl_xor(s2, m);
  }
  const float mu  = s1 * (1.f / 128.f);
  const float var = s2 * (1.f / 128.f) - mu * mu;
  const float inv = rsqrtf(var + 1e-5f);

  out[row * 128 + lane]      = (h0 - mu) * inv * lng[lane] + lnb[lane];
  out[row * 128 + 64 + lane] = (h1 - mu) * inv * lng[lane + 64] + lnb[lane + 64];
}

// ---------------------------------------------------------------------------
extern "C" void kernel_launch(void* const* d_in, const int* in_sizes, int n_in,
                              void* d_out, int out_size, void* d_ws, size_t ws_size,
                              hipStream_t stream) {
  const float* x   = (const float*)d_in[0];
  const int*   ei  = (const int*)d_in[1];
  const float* ea  = (const float*)d_in[2];
  const float* Wq  = (const float*)d_in[3];
  const float* bq  = (const float*)d_in[4];
  const float* Wk  = (const float*)d_in[5];
  const float* bk  = (const float*)d_in[6];
  const float* Wv  = (const float*)d_in[7];
  const float* bv  = (const float*)d_in[8];
  const float* Wf  = (const float*)d_in[9];
  const float* bf  = (const float*)d_in[10];
  const float* Wo  = (const float*)d_in[11];
  const float* bo  = (const float*)d_in[12];
  const float* lng = (const float*)d_in[13];
  const float* lnb = (const float*)d_in[14];
  float* out = (float*)d_out;

  const size_t NQ = (size_t)B_ * N_ * HID_;  // 5,120,000
  float* ws  = (float*)d_ws;
  float* Q   = ws;
  float* Kt  = ws + NQ;
  float* V   = ws + 2 * NQ;
  float* agg = ws + 3 * NQ;
  float* ex  = ws + 4 * NQ;                       // E*16 = 2,560,000 floats
  int*   ib  = (int*)(ws + 4 * NQ + (size_t)E_ * 16);
  int*   cnt    = ib;                             // N
  int*   rowptr = ib + N_;                        // N+1
  int*   fill   = ib + 2 * N_ + 1;                // N
  int*   eord   = ib + 3 * N_ + 1;                // E

  hipMemsetAsync(cnt, 0, N_ * sizeof(int), stream);

  qkv_proj<<<(B_ * N_) / 8, 256, 0, stream>>>(x, Wq, bq, Wk, bk, Wv, bv, Q, Kt, V);
  csr_hist<<<(E_ + 255) / 256, 256, 0, stream>>>(ei, cnt);
  csr_scan<<<1, 1024, 0, stream>>>(cnt, rowptr, fill);
  csr_scatter<<<(E_ + 255) / 256, 256, 0, stream>>>(ei, fill, eord);
  edge_logits<<<E_ / 64, 256, 0, stream>>>(ei, ea, Wf, bf, Q, Kt, ex);
  agg_gather<<<N_, 256, 0, stream>>>(ei, rowptr, eord, ex, V, agg);
  out_ln<<<(B_ * N_) / 4, 256, 0, stream>>>(agg, Wo, bo, x, lng, lnb, out);
}

// Round 3
// 287.674 us; speedup vs baseline: 8.9047x; 1.4822x over previous
//
#include <hip/hip_runtime.h>
#include <hip/hip_bf16.h>

#define B_ 4
#define N_ 10000
#define E_ 160000
#define D_ 128
#define H_ 4
#define HID_ 128
#define DK_ 32
#define DE_ 16

typedef __attribute__((ext_vector_type(8))) short short8v;
typedef __attribute__((ext_vector_type(4))) short short4v;
typedef __attribute__((ext_vector_type(4))) float f32x4;

// fp32 -> bf16 bits, round-to-nearest-even
__device__ __forceinline__ short bfb(float f) {
  union { float f; unsigned u; } c; c.f = f;
  unsigned u = c.u + 0x7FFFu + ((c.u >> 16) & 1u);
  return (short)(u >> 16);
}

// ---------------------------------------------------------------------------
// P0: W^T bf16 prep. wt[m][n][k] = bf16(W_m[k*128+n]),  m: 0=q 1=k 2=v 3=o
// ---------------------------------------------------------------------------
__global__ __launch_bounds__(256) void wt_prep(
    const float* __restrict__ Wq, const float* __restrict__ Wk,
    const float* __restrict__ Wv, const float* __restrict__ Wo,
    short* __restrict__ wt) {
  const float* Ws[4] = {Wq, Wk, Wv, Wo};
  const int i = blockIdx.x * 256 + threadIdx.x;   // 0..65535
  const int m = i >> 14;
  const int k = (i >> 7) & 127;
  const int n = i & 127;                           // n fast -> coalesced read
  wt[(size_t)m * 16384 + n * 128 + k] = bfb(Ws[m][k * 128 + n]);
}

// ---------------------------------------------------------------------------
// K1: QKV projection via MFMA. block = 256 (4 waves), 64 rows/block.
// Wave w owns rows w*16..w*16+15, all 128 cols, 3 matrices sequentially.
// A frag: xs[w*16 + (lane&15)][kk*32 + (lane>>4)*8 + j]
// B frag: Wt[n=cb*16+(lane&15)][kk*32 + (lane>>4)*8 + j]   (contiguous 16B)
// D: row (lane>>4)*4+r, col cb*16+(lane&15)
// ---------------------------------------------------------------------------
__global__ __launch_bounds__(256) void qkv_mfma(
    const float* __restrict__ x, const short* __restrict__ wt,
    const float* __restrict__ bq, const float* __restrict__ bk,
    const float* __restrict__ bv,
    float* __restrict__ Q, float* __restrict__ Kt, float* __restrict__ V) {
  __shared__ short xs[64][136];                    // +8 pad: banks spread
  const int tid  = threadIdx.x;
  const int lane = tid & 63;
  const int wave = tid >> 6;
  const int ln15 = lane & 15;
  const int g    = lane >> 4;                      // 0..3
  const long rowBase = (long)blockIdx.x * 64;

  // stage + convert: 64x128 fp32 -> bf16
  for (int i = tid; i < 64 * 32; i += 256) {
    const int r  = i >> 5;
    const int c4 = (i & 31) * 4;
    const float4 v = *(const float4*)(x + (rowBase + r) * 128 + c4);
    short4v sv; sv.x = bfb(v.x); sv.y = bfb(v.y); sv.z = bfb(v.z); sv.w = bfb(v.w);
    *(short4v*)&xs[r][c4] = sv;
  }
  __syncthreads();

  // A fragments (shared across the 3 matrices)
  short8v af[4];
#pragma unroll
  for (int kk = 0; kk < 4; ++kk)
    af[kk] = *(const short8v*)&xs[wave * 16 + ln15][kk * 32 + g * 8];

  const float* bs[3] = {bq, bk, bv};
  float* Os[3] = {Q, Kt, V};

#pragma unroll
  for (int m = 0; m < 3; ++m) {
    const short* Wt = wt + (size_t)m * 16384;
    f32x4 acc[8];
#pragma unroll
    for (int cb = 0; cb < 8; ++cb) acc[cb] = (f32x4){0.f, 0.f, 0.f, 0.f};

#pragma unroll
    for (int kk = 0; kk < 4; ++kk) {
#pragma unroll
      for (int cb = 0; cb < 8; ++cb) {
        const short8v bfr =
            *(const short8v*)(Wt + (cb * 16 + ln15) * 128 + kk * 32 + g * 8);
        acc[cb] = __builtin_amdgcn_mfma_f32_16x16x32_bf16(af[kk], bfr, acc[cb], 0, 0, 0);
      }
    }

    float* O = Os[m];
    const float* bias = bs[m];
#pragma unroll
    for (int cb = 0; cb < 8; ++cb) {
      const int col = cb * 16 + ln15;
      const float bv_ = bias[col];
#pragma unroll
      for (int r = 0; r < 4; ++r) {
        const long row = rowBase + wave * 16 + g * 4 + r;
        O[row * 128 + col] = acc[cb][r] + bv_;
      }
    }
  }
}

// ---------------------------------------------------------------------------
// CSR build: histogram by dst -> exclusive scan -> bucket scatter
// ---------------------------------------------------------------------------
__global__ __launch_bounds__(256) void csr_hist(const int* __restrict__ ei,
                                                int* __restrict__ cnt) {
  const int e = blockIdx.x * 256 + threadIdx.x;
  if (e < E_) atomicAdd(&cnt[ei[E_ + e]], 1);
}

__global__ __launch_bounds__(1024) void csr_scan(const int* __restrict__ cnt,
                                                 int* __restrict__ rowptr,
                                                 int* __restrict__ fill) {
  __shared__ int part[1024];
  const int t = threadIdx.x;
  int local[10];
  int sum = 0;
#pragma unroll
  for (int i = 0; i < 10; ++i) {
    const int idx = t * 10 + i;
    local[i] = sum;
    sum += (idx < N_) ? cnt[idx] : 0;
  }
  part[t] = sum;
  __syncthreads();
  for (int off = 1; off < 1024; off <<= 1) {
    const int v = (t >= off) ? part[t - off] : 0;
    __syncthreads();
    part[t] += v;
    __syncthreads();
  }
  const int excl = (t == 0) ? 0 : part[t - 1];
#pragma unroll
  for (int i = 0; i < 10; ++i) {
    const int idx = t * 10 + i;
    if (idx <= N_) {
      const int o = excl + local[i];
      rowptr[idx] = o;
      if (idx < N_) fill[idx] = o;
    }
  }
}

__global__ __launch_bounds__(256) void csr_scatter(const int* __restrict__ ei,
                                                   int* __restrict__ fill,
                                                   int* __restrict__ eord) {
  const int e = blockIdx.x * 256 + threadIdx.x;
  if (e < E_) {
    const int dst = ei[E_ + e];
    const int pos = atomicAdd(&fill[dst], 1);
    eord[pos] = e;
  }
}

// ---------------------------------------------------------------------------
// K2: per-edge FiLM + logits + exp (no max pass: logits are O(0.05) so
// exp(lg)/sum(exp(lg)) == reference softmax up to fp32 rounding).
// ---------------------------------------------------------------------------
__global__ __launch_bounds__(256) void edge_logits(
    const int* __restrict__ ei, const float* __restrict__ ea,
    const float* __restrict__ Wf, const float* __restrict__ bf,
    const float* __restrict__ Q, const float* __restrict__ Kt,
    float* __restrict__ ex) {
  __shared__ float wf[16 * 256];
  __shared__ float bfs[256];
  __shared__ float gb[4][256];  // per-wave gamma(0..127) / beta(128..255)

  const int tid = threadIdx.x;
  for (int i = tid; i < 16 * 256; i += 256) wf[i] = Wf[i];
  if (tid < 256) bfs[tid] = bf[tid];
  __syncthreads();

  const int lane = tid & 63;
  const int wave = tid >> 6;
  const int b = lane >> 4, h = (lane >> 2) & 3, q = lane & 3;
  const int cbase = h * 32 + q * 8;

  const float4* wf4  = (const float4*)wf;
  const float4* bfs4 = (const float4*)bfs;

  for (int it = 0; it < 16; ++it) {
    const int e = blockIdx.x * 64 + it * 4 + wave;
    const int src = ei[e];
    const int dst = ei[E_ + e];

    float eav[16];
    {
      const float4* eap = (const float4*)(ea + (size_t)e * 16);
      float4 t0 = eap[0], t1 = eap[1], t2 = eap[2], t3 = eap[3];
      eav[0]=t0.x; eav[1]=t0.y; eav[2]=t0.z; eav[3]=t0.w;
      eav[4]=t1.x; eav[5]=t1.y; eav[6]=t1.z; eav[7]=t1.w;
      eav[8]=t2.x; eav[9]=t2.y; eav[10]=t2.z; eav[11]=t2.w;
      eav[12]=t3.x; eav[13]=t3.y; eav[14]=t3.z; eav[15]=t3.w;
    }

    float4 accg = bfs4[lane];
#pragma unroll
    for (int de = 0; de < 16; ++de) {
      const float ev = eav[de];
      const float4 w = wf4[de * 64 + lane];
      accg.x = fmaf(ev, w.x, accg.x);
      accg.y = fmaf(ev, w.y, accg.y);
      accg.z = fmaf(ev, w.z, accg.z);
      accg.w = fmaf(ev, w.w, accg.w);
    }
    ((float4*)gb[wave])[lane] = accg;
    __syncthreads();

    const float4* gbp = (const float4*)gb[wave];
    const float4 g0 = gbp[(cbase >> 2)];
    const float4 g1 = gbp[(cbase >> 2) + 1];
    const float4 t0 = gbp[32 + (cbase >> 2)];
    const float4 t1 = gbp[32 + (cbase >> 2) + 1];

    const size_t qoff = ((size_t)b * N_ + dst) * 128 + cbase;
    const size_t koff = ((size_t)b * N_ + src) * 128 + cbase;
    const float4 q0 = *(const float4*)(Q + qoff);
    const float4 q1 = *(const float4*)(Q + qoff + 4);
    const float4 k0 = *(const float4*)(Kt + koff);
    const float4 k1 = *(const float4*)(Kt + koff + 4);

    float p = 0.f;
    p = fmaf(q0.x, fmaf(k0.x, 1.f + g0.x, t0.x), p);
    p = fmaf(q0.y, fmaf(k0.y, 1.f + g0.y, t0.y), p);
    p = fmaf(q0.z, fmaf(k0.z, 1.f + g0.z, t0.z), p);
    p = fmaf(q0.w, fmaf(k0.w, 1.f + g0.w, t0.w), p);
    p = fmaf(q1.x, fmaf(k1.x, 1.f + g1.x, t1.x), p);
    p = fmaf(q1.y, fmaf(k1.y, 1.f + g1.y, t1.y), p);
    p = fmaf(q1.z, fmaf(k1.z, 1.f + g1.z, t1.z), p);
    p = fmaf(q1.w, fmaf(k1.w, 1.f + g1.w, t1.w), p);

    p += __shfl_xor(p, 1);
    p += __shfl_xor(p, 2);

    const float lg = p * 0.17677669529663687f;  // 1/sqrt(32)
    if (q == 0) ex[(size_t)e * 16 + b * 4 + h] = __expf(lg);
    __syncthreads();
  }
}

// ---------------------------------------------------------------------------
// K3: CSR gather aggregation. block per node; wave = batch.
// ---------------------------------------------------------------------------
__global__ __launch_bounds__(256) void agg_gather(
    const int* __restrict__ ei, const int* __restrict__ rowptr,
    const int* __restrict__ eord, const float* __restrict__ ex,
    const float* __restrict__ V, float* __restrict__ agg) {
  const int node = blockIdx.x;
  const int lane = threadIdx.x & 63;
  const int b    = threadIdx.x >> 6;
  const int beg = rowptr[node], end = rowptr[node + 1];

  const int myh = lane & 3;
  float se = 0.f;
  for (int i = beg; i < end; ++i) {
    const int e = eord[i];
    se += ex[(size_t)e * 16 + b * 4 + myh];
  }
  const int h0 = lane >> 5;
  const float inv0 = 1.f / __shfl(se, h0);
  const float inv1 = 1.f / __shfl(se, 2 + h0);

  float acc0 = 0.f, acc1 = 0.f;
  for (int i = beg; i < end; ++i) {
    const int e = eord[i];
    const int src = ei[e];
    const float* exp_ = ex + (size_t)e * 16 + b * 4;
    const float a0 = exp_[h0] * inv0;
    const float a1 = exp_[2 + h0] * inv1;
    const float* vp = V + ((size_t)b * N_ + src) * 128;
    acc0 = fmaf(a0, vp[lane], acc0);
    acc1 = fmaf(a1, vp[lane + 64], acc1);
  }
  float* ap = agg + ((size_t)b * N_ + node) * 128;
  ap[lane]      = acc0;
  ap[lane + 64] = acc1;
}

// ---------------------------------------------------------------------------
// K4: y = agg @ Wo + bo (MFMA); h = x + y; LayerNorm(h) -> out
// block = 256 (4 waves), 64 rows/block, wave owns 16 rows.
// ---------------------------------------------------------------------------
__global__ __launch_bounds__(256) void out_ln_mfma(
    const float* __restrict__ agg, const short* __restrict__ wto,
    const float* __restrict__ bo, const float* __restrict__ x,
    const float* __restrict__ lng, const float* __restrict__ lnb,
    float* __restrict__ out) {
  __shared__ short as_[64][136];
  const int tid  = threadIdx.x;
  const int lane = tid & 63;
  const int wave = tid >> 6;
  const int ln15 = lane & 15;
  const int g    = lane >> 4;
  const long rowBase = (long)blockIdx.x * 64;

  for (int i = tid; i < 64 * 32; i += 256) {
    const int r  = i >> 5;
    const int c4 = (i & 31) * 4;
    const float4 v = *(const float4*)(agg + (rowBase + r) * 128 + c4);
    short4v sv; sv.x = bfb(v.x); sv.y = bfb(v.y); sv.z = bfb(v.z); sv.w = bfb(v.w);
    *(short4v*)&as_[r][c4] = sv;
  }
  __syncthreads();

  short8v af[4];
#pragma unroll
  for (int kk = 0; kk < 4; ++kk)
    af[kk] = *(const short8v*)&as_[wave * 16 + ln15][kk * 32 + g * 8];

  f32x4 acc[8];
#pragma unroll
  for (int cb = 0; cb < 8; ++cb) acc[cb] = (f32x4){0.f, 0.f, 0.f, 0.f};

#pragma unroll
  for (int kk = 0; kk < 4; ++kk) {
#pragma unroll
    for (int cb = 0; cb < 8; ++cb) {
      const short8v bfr =
          *(const short8v*)(wto + (cb * 16 + ln15) * 128 + kk * 32 + g * 8);
      acc[cb] = __builtin_amdgcn_mfma_f32_16x16x32_bf16(af[kk], bfr, acc[cb], 0, 0, 0);
    }
  }

  // h = y + bo + x  (keep in acc), then per-row LN reduction
#pragma unroll
  for (int cb = 0; cb < 8; ++cb) {
    const int col = cb * 16 + ln15;
    const float bov = bo[col];
#pragma unroll
    for (int r = 0; r < 4; ++r) {
      const long row = rowBase + wave * 16 + g * 4 + r;
      acc[cb][r] += bov + x[row * 128 + col];
    }
  }

  float s1[4], s2[4];
#pragma unroll
  for (int r = 0; r < 4; ++r) {
    s1[r] = 0.f; s2[r] = 0.f;
#pragma unroll
    for (int cb = 0; cb < 8; ++cb) {
      s1[r] += acc[cb][r];
      s2[r] = fmaf(acc[cb][r], acc[cb][r], s2[r]);
    }
  }
#pragma unroll
  for (int m = 1; m < 16; m <<= 1) {
#pragma unroll
    for (int r = 0; r < 4; ++r) {
      s1[r] += __shfl_xor(s1[r], m);
      s2[r] += __shfl_xor(s2[r], m);
    }
  }
  float mu[4], inv[4];
#pragma unroll
  for (int r = 0; r < 4; ++r) {
    mu[r] = s1[r] * (1.f / 128.f);
    const float var = s2[r] * (1.f / 128.f) - mu[r] * mu[r];
    inv[r] = rsqrtf(var + 1e-5f);
  }

#pragma unroll
  for (int cb = 0; cb < 8; ++cb) {
    const int col = cb * 16 + ln15;
    const float gv = lng[col], bv_ = lnb[col];
#pragma unroll
    for (int r = 0; r < 4; ++r) {
      const long row = rowBase + wave * 16 + g * 4 + r;
      out[row * 128 + col] = (acc[cb][r] - mu[r]) * inv[r] * gv + bv_;
    }
  }
}

// ---------------------------------------------------------------------------
extern "C" void kernel_launch(void* const* d_in, const int* in_sizes, int n_in,
                              void* d_out, int out_size, void* d_ws, size_t ws_size,
                              hipStream_t stream) {
  const float* x   = (const float*)d_in[0];
  const int*   ei  = (const int*)d_in[1];
  const float* ea  = (const float*)d_in[2];
  const float* Wq  = (const float*)d_in[3];
  const float* bq  = (const float*)d_in[4];
  const float* Wk  = (const float*)d_in[5];
  const float* bk  = (const float*)d_in[6];
  const float* Wv  = (const float*)d_in[7];
  const float* bv  = (const float*)d_in[8];
  const float* Wf  = (const float*)d_in[9];
  const float* bf  = (const float*)d_in[10];
  const float* Wo  = (const float*)d_in[11];
  const float* bo  = (const float*)d_in[12];
  const float* lng = (const float*)d_in[13];
  const float* lnb = (const float*)d_in[14];
  float* out = (float*)d_out;

  const size_t NQ = (size_t)B_ * N_ * HID_;  // 5,120,000
  float* ws  = (float*)d_ws;
  float* Q   = ws;
  float* Kt  = ws + NQ;
  float* V   = ws + 2 * NQ;
  float* agg = ws + 3 * NQ;
  float* ex  = ws + 4 * NQ;                       // E*16 floats
  int*   ib  = (int*)(ws + 4 * NQ + (size_t)E_ * 16);
  int*   cnt    = ib;                             // N
  int*   rowptr = ib + N_;                        // N+1
  int*   fill   = ib + 2 * N_ + 1;                // N
  int*   eord   = ib + 3 * N_ + 1;                // E
  short* wt     = (short*)(eord + E_);            // 4*128*128 bf16

  hipMemsetAsync(cnt, 0, N_ * sizeof(int), stream);

  wt_prep<<<256, 256, 0, stream>>>(Wq, Wk, Wv, Wo, wt);
  qkv_mfma<<<(B_ * N_) / 64, 256, 0, stream>>>(x, wt, bq, bk, bv, Q, Kt, V);
  csr_hist<<<(E_ + 255) / 256, 256, 0, stream>>>(ei, cnt);
  csr_scan<<<1, 1024, 0, stream>>>(cnt, rowptr, fill);
  csr_scatter<<<(E_ + 255) / 256, 256, 0, stream>>>(ei, fill, eord);
  edge_logits<<<E_ / 64, 256, 0, stream>>>(ei, ea, Wf, bf, Q, Kt, ex);
  agg_gather<<<N_, 256, 0, stream>>>(ei, rowptr, eord, ex, V, agg);
  out_ln_mfma<<<(B_ * N_) / 64, 256, 0, stream>>>(agg, wt + 3 * 16384, bo, x, lng, lnb, out);
}

// Round 4
// 237.263 us; speedup vs baseline: 10.7967x; 1.2125x over previous
//
#include <hip/hip_runtime.h>
#include <hip/hip_bf16.h>

#define B_ 4
#define N_ 10000
#define E_ 160000
#define D_ 128
#define H_ 4
#define HID_ 128
#define DK_ 32
#define DE_ 16

typedef __attribute__((ext_vector_type(8))) short short8v;
typedef __attribute__((ext_vector_type(4))) short short4v;
typedef __attribute__((ext_vector_type(4))) float f32x4;

// fp32 -> bf16 bits, round-to-nearest-even
__device__ __forceinline__ short bfb(float f) {
  union { float f; unsigned u; } c; c.f = f;
  unsigned u = c.u + 0x7FFFu + ((c.u >> 16) & 1u);
  return (short)(u >> 16);
}
// bf16 bits -> fp32
__device__ __forceinline__ float b2f(unsigned short u) {
  union { unsigned u; float f; } c; c.u = ((unsigned)u) << 16;
  return c.f;
}

// ---------------------------------------------------------------------------
// P0: W^T bf16 prep. wt[m][n][k] = bf16(W_m[k*128+n]),  m: 0=q 1=k 2=v 3=o
// ---------------------------------------------------------------------------
__global__ __launch_bounds__(256) void wt_prep(
    const float* __restrict__ Wq, const float* __restrict__ Wk,
    const float* __restrict__ Wv, const float* __restrict__ Wo,
    short* __restrict__ wt) {
  const float* Ws[4] = {Wq, Wk, Wv, Wo};
  const int i = blockIdx.x * 256 + threadIdx.x;   // 0..65535
  const int m = i >> 14;
  const int k = (i >> 7) & 127;
  const int n = i & 127;
  wt[(size_t)m * 16384 + n * 128 + k] = bfb(Ws[m][k * 128 + n]);
}

// ---------------------------------------------------------------------------
// K1: QKV projection via MFMA. block = 256 (4 waves), 64 rows/block.
// Q -> fp32 [b][n][128]; K,V -> bf16 kv[n][b][0:128 | 128:256]
// ---------------------------------------------------------------------------
__global__ __launch_bounds__(256) void qkv_mfma(
    const float* __restrict__ x, const short* __restrict__ wt,
    const float* __restrict__ bq, const float* __restrict__ bk,
    const float* __restrict__ bv,
    float* __restrict__ Q, short* __restrict__ kv) {
  __shared__ short xs[64][136];
  const int tid  = threadIdx.x;
  const int lane = tid & 63;
  const int wave = tid >> 6;
  const int ln15 = lane & 15;
  const int g    = lane >> 4;
  const long rowBase = (long)blockIdx.x * 64;

  for (int i = tid; i < 64 * 32; i += 256) {
    const int r  = i >> 5;
    const int c4 = (i & 31) * 4;
    const float4 v = *(const float4*)(x + (rowBase + r) * 128 + c4);
    short4v sv; sv.x = bfb(v.x); sv.y = bfb(v.y); sv.z = bfb(v.z); sv.w = bfb(v.w);
    *(short4v*)&xs[r][c4] = sv;
  }
  __syncthreads();

  short8v af[4];
#pragma unroll
  for (int kk = 0; kk < 4; ++kk)
    af[kk] = *(const short8v*)&xs[wave * 16 + ln15][kk * 32 + g * 8];

  const float* bs[3] = {bq, bk, bv};

#pragma unroll
  for (int m = 0; m < 3; ++m) {
    const short* Wt = wt + (size_t)m * 16384;
    f32x4 acc[8];
#pragma unroll
    for (int cb = 0; cb < 8; ++cb) acc[cb] = (f32x4){0.f, 0.f, 0.f, 0.f};

#pragma unroll
    for (int kk = 0; kk < 4; ++kk) {
#pragma unroll
      for (int cb = 0; cb < 8; ++cb) {
        const short8v bfr =
            *(const short8v*)(Wt + (cb * 16 + ln15) * 128 + kk * 32 + g * 8);
        acc[cb] = __builtin_amdgcn_mfma_f32_16x16x32_bf16(af[kk], bfr, acc[cb], 0, 0, 0);
      }
    }

    const float* bias = bs[m];
#pragma unroll
    for (int cb = 0; cb < 8; ++cb) {
      const int col = cb * 16 + ln15;
      const float bv_ = bias[col];
#pragma unroll
      for (int r = 0; r < 4; ++r) {
        const long row = rowBase + wave * 16 + g * 4 + r;
        const float val = acc[cb][r] + bv_;
        if (m == 0) {
          Q[row * 128 + col] = val;
        } else {
          const int bb = (int)(row / N_);
          const int nn = (int)(row - (long)bb * N_);
          kv[((size_t)nn * 4 + bb) * 256 + (m - 1) * 128 + col] = bfb(val);
        }
      }
    }
  }
}

// ---------------------------------------------------------------------------
// CSR build
// ---------------------------------------------------------------------------
__global__ __launch_bounds__(256) void csr_hist(const int* __restrict__ ei,
                                                int* __restrict__ cnt) {
  const int e = blockIdx.x * 256 + threadIdx.x;
  if (e < E_) atomicAdd(&cnt[ei[E_ + e]], 1);
}

__global__ __launch_bounds__(1024) void csr_scan(const int* __restrict__ cnt,
                                                 int* __restrict__ rowptr,
                                                 int* __restrict__ fill) {
  __shared__ int part[1024];
  const int t = threadIdx.x;
  int local[10];
  int sum = 0;
#pragma unroll
  for (int i = 0; i < 10; ++i) {
    const int idx = t * 10 + i;
    local[i] = sum;
    sum += (idx < N_) ? cnt[idx] : 0;
  }
  part[t] = sum;
  __syncthreads();
  for (int off = 1; off < 1024; off <<= 1) {
    const int v = (t >= off) ? part[t - off] : 0;
    __syncthreads();
    part[t] += v;
    __syncthreads();
  }
  const int excl = (t == 0) ? 0 : part[t - 1];
#pragma unroll
  for (int i = 0; i < 10; ++i) {
    const int idx = t * 10 + i;
    if (idx <= N_) {
      const int o = excl + local[i];
      rowptr[idx] = o;
      if (idx < N_) fill[idx] = o;
    }
  }
}

// scatter: CSR-ordered src + CSR-ordered copy of edge_attr
__global__ __launch_bounds__(256) void csr_scatter(
    const int* __restrict__ ei, const float* __restrict__ ea,
    int* __restrict__ fill, int* __restrict__ esrc, float* __restrict__ eas) {
  const int e = blockIdx.x * 256 + threadIdx.x;
  if (e < E_) {
    const int dst = ei[E_ + e];
    const int pos = atomicAdd(&fill[dst], 1);
    esrc[pos] = ei[e];
    const float4* s4 = (const float4*)(ea + (size_t)e * 16);
    float4* d4 = (float4*)(eas + (size_t)pos * 16);
    d4[0] = s4[0]; d4[1] = s4[1]; d4[2] = s4[2]; d4[3] = s4[3];
  }
}

// ---------------------------------------------------------------------------
// K2: fused FiLM + logits + softmax + aggregation. block per node, wave = b.
// lane owns dims {lane, lane+64}: head(lane) = lane>>5, head(lane+64) = 2+(lane>>5).
// Single pass: acc = sum(ex * V), se = sum(ex); agg = acc/se. (No max pass:
// logits are O(0.05) so exp(lg)/sum == reference softmax to fp32 rounding.)
// ---------------------------------------------------------------------------
__global__ __launch_bounds__(256) void fused_attn(
    const int* __restrict__ rowptr, const int* __restrict__ esrc,
    const float* __restrict__ eas, const float* __restrict__ Wf,
    const float* __restrict__ bf, const float* __restrict__ Q,
    const short* __restrict__ kv, float* __restrict__ agg) {
  const int node = blockIdx.x;
  const int lane = threadIdx.x & 63;
  const int b    = threadIdx.x >> 6;

  // Wf columns for my 2 gamma dims + 2 beta dims, in registers
  float wg0[16], wg1[16], wb0[16], wb1[16];
#pragma unroll
  for (int j = 0; j < 16; ++j) {
    wg0[j] = Wf[j * 256 + lane];
    wg1[j] = Wf[j * 256 + 64 + lane];
    wb0[j] = Wf[j * 256 + 128 + lane];
    wb1[j] = Wf[j * 256 + 192 + lane];
  }
  const float bg0 = bf[lane], bg1 = bf[64 + lane];
  const float bb0 = bf[128 + lane], bb1 = bf[192 + lane];

  const float* qp = Q + ((size_t)b * N_ + node) * 128;
  const float q0 = qp[lane];
  const float q1 = qp[64 + lane];

  const int beg = rowptr[node], end = rowptr[node + 1];
  float acc0 = 0.f, acc1 = 0.f, se0 = 0.f, se1 = 0.f;

  for (int i = beg; i < end; ++i) {
    const int src = esrc[i];
    const float4 a0 = *(const float4*)(eas + (size_t)i * 16);
    const float4 a1 = *(const float4*)(eas + (size_t)i * 16 + 4);
    const float4 a2 = *(const float4*)(eas + (size_t)i * 16 + 8);
    const float4 a3 = *(const float4*)(eas + (size_t)i * 16 + 12);
    const float ev[16] = {a0.x, a0.y, a0.z, a0.w, a1.x, a1.y, a1.z, a1.w,
                          a2.x, a2.y, a2.z, a2.w, a3.x, a3.y, a3.z, a3.w};
    float g0 = bg0, g1 = bg1, h0 = bb0, h1 = bb1;
#pragma unroll
    for (int j = 0; j < 16; ++j) {
      g0 = fmaf(ev[j], wg0[j], g0);
      g1 = fmaf(ev[j], wg1[j], g1);
      h0 = fmaf(ev[j], wb0[j], h0);
      h1 = fmaf(ev[j], wb1[j], h1);
    }

    const unsigned short* kp = (const unsigned short*)(kv + ((size_t)src * 4 + b) * 256);
    const float k0 = b2f(kp[lane]);
    const float k1 = b2f(kp[64 + lane]);
    const float v0 = b2f(kp[128 + lane]);
    const float v1 = b2f(kp[192 + lane]);

    float p0 = q0 * fmaf(k0, 1.f + g0, h0);
    float p1 = q1 * fmaf(k1, 1.f + g1, h1);
#pragma unroll
    for (int m = 1; m < 32; m <<= 1) {
      p0 += __shfl_xor(p0, m);
      p1 += __shfl_xor(p1, m);
    }
    const float ex0 = __expf(p0 * 0.17677669529663687f);
    const float ex1 = __expf(p1 * 0.17677669529663687f);
    se0 += ex0; se1 += ex1;
    acc0 = fmaf(ex0, v0, acc0);
    acc1 = fmaf(ex1, v1, acc1);
  }

  float* ap = agg + ((size_t)b * N_ + node) * 128;
  ap[lane]      = (end > beg) ? acc0 / se0 : 0.f;
  ap[64 + lane] = (end > beg) ? acc1 / se1 : 0.f;
}

// ---------------------------------------------------------------------------
// K4: y = agg @ Wo + bo (MFMA); h = x + y; LayerNorm(h) -> out
// ---------------------------------------------------------------------------
__global__ __launch_bounds__(256) void out_ln_mfma(
    const float* __restrict__ agg, const short* __restrict__ wto,
    const float* __restrict__ bo, const float* __restrict__ x,
    const float* __restrict__ lng, const float* __restrict__ lnb,
    float* __restrict__ out) {
  __shared__ short as_[64][136];
  const int tid  = threadIdx.x;
  const int lane = tid & 63;
  const int wave = tid >> 6;
  const int ln15 = lane & 15;
  const int g    = lane >> 4;
  const long rowBase = (long)blockIdx.x * 64;

  for (int i = tid; i < 64 * 32; i += 256) {
    const int r  = i >> 5;
    const int c4 = (i & 31) * 4;
    const float4 v = *(const float4*)(agg + (rowBase + r) * 128 + c4);
    short4v sv; sv.x = bfb(v.x); sv.y = bfb(v.y); sv.z = bfb(v.z); sv.w = bfb(v.w);
    *(short4v*)&as_[r][c4] = sv;
  }
  __syncthreads();

  short8v af[4];
#pragma unroll
  for (int kk = 0; kk < 4; ++kk)
    af[kk] = *(const short8v*)&as_[wave * 16 + ln15][kk * 32 + g * 8];

  f32x4 acc[8];
#pragma unroll
  for (int cb = 0; cb < 8; ++cb) acc[cb] = (f32x4){0.f, 0.f, 0.f, 0.f};

#pragma unroll
  for (int kk = 0; kk < 4; ++kk) {
#pragma unroll
    for (int cb = 0; cb < 8; ++cb) {
      const short8v bfr =
          *(const short8v*)(wto + (cb * 16 + ln15) * 128 + kk * 32 + g * 8);
      acc[cb] = __builtin_amdgcn_mfma_f32_16x16x32_bf16(af[kk], bfr, acc[cb], 0, 0, 0);
    }
  }

#pragma unroll
  for (int cb = 0; cb < 8; ++cb) {
    const int col = cb * 16 + ln15;
    const float bov = bo[col];
#pragma unroll
    for (int r = 0; r < 4; ++r) {
      const long row = rowBase + wave * 16 + g * 4 + r;
      acc[cb][r] += bov + x[row * 128 + col];
    }
  }

  float s1[4], s2[4];
#pragma unroll
  for (int r = 0; r < 4; ++r) {
    s1[r] = 0.f; s2[r] = 0.f;
#pragma unroll
    for (int cb = 0; cb < 8; ++cb) {
      s1[r] += acc[cb][r];
      s2[r] = fmaf(acc[cb][r], acc[cb][r], s2[r]);
    }
  }
#pragma unroll
  for (int m = 1; m < 16; m <<= 1) {
#pragma unroll
    for (int r = 0; r < 4; ++r) {
      s1[r] += __shfl_xor(s1[r], m);
      s2[r] += __shfl_xor(s2[r], m);
    }
  }
  float mu[4], inv[4];
#pragma unroll
  for (int r = 0; r < 4; ++r) {
    mu[r] = s1[r] * (1.f / 128.f);
    const float var = s2[r] * (1.f / 128.f) - mu[r] * mu[r];
    inv[r] = rsqrtf(var + 1e-5f);
  }

#pragma unroll
  for (int cb = 0; cb < 8; ++cb) {
    const int col = cb * 16 + ln15;
    const float gv = lng[col], bv_ = lnb[col];
#pragma unroll
    for (int r = 0; r < 4; ++r) {
      const long row = rowBase + wave * 16 + g * 4 + r;
      out[row * 128 + col] = (acc[cb][r] - mu[r]) * inv[r] * gv + bv_;
    }
  }
}

// ---------------------------------------------------------------------------
extern "C" void kernel_launch(void* const* d_in, const int* in_sizes, int n_in,
                              void* d_out, int out_size, void* d_ws, size_t ws_size,
                              hipStream_t stream) {
  const float* x   = (const float*)d_in[0];
  const int*   ei  = (const int*)d_in[1];
  const float* ea  = (const float*)d_in[2];
  const float* Wq  = (const float*)d_in[3];
  const float* bq  = (const float*)d_in[4];
  const float* Wk  = (const float*)d_in[5];
  const float* bk  = (const float*)d_in[6];
  const float* Wv  = (const float*)d_in[7];
  const float* bv  = (const float*)d_in[8];
  const float* Wf  = (const float*)d_in[9];
  const float* bf  = (const float*)d_in[10];
  const float* Wo  = (const float*)d_in[11];
  const float* bo  = (const float*)d_in[12];
  const float* lng = (const float*)d_in[13];
  const float* lnb = (const float*)d_in[14];
  float* out = (float*)d_out;

  const size_t NQ = (size_t)B_ * N_ * HID_;  // 5,120,000
  float* ws   = (float*)d_ws;
  float* Q    = ws;                                  // NQ floats
  float* agg  = ws + NQ;                             // NQ floats
  float* eas  = ws + 2 * NQ;                         // E*16 floats
  short* kv   = (short*)(ws + 2 * NQ + (size_t)E_ * 16);  // B*N*256 shorts
  int*   ib   = (int*)(kv + (size_t)B_ * N_ * 256);
  int*   cnt    = ib;                                // N
  int*   rowptr = ib + N_;                           // N+1
  int*   fill   = ib + 2 * N_ + 1;                   // N
  int*   esrc   = ib + 3 * N_ + 1;                   // E
  short* wt     = (short*)(esrc + E_);               // 4*128*128 bf16

  hipMemsetAsync(cnt, 0, N_ * sizeof(int), stream);

  wt_prep<<<256, 256, 0, stream>>>(Wq, Wk, Wv, Wo, wt);
  qkv_mfma<<<(B_ * N_) / 64, 256, 0, stream>>>(x, wt, bq, bk, bv, Q, kv);
  csr_hist<<<(E_ + 255) / 256, 256, 0, stream>>>(ei, cnt);
  csr_scan<<<1, 1024, 0, stream>>>(cnt, rowptr, fill);
  csr_scatter<<<(E_ + 255) / 256, 256, 0, stream>>>(ei, ea, fill, esrc, eas);
  fused_attn<<<N_, 256, 0, stream>>>(rowptr, esrc, eas, Wf, bf, Q, kv, agg);
  out_ln_mfma<<<(B_ * N_) / 64, 256, 0, stream>>>(agg, wt + 3 * 16384, bo, x, lng, lnb, out);
}